// Round 6
// baseline (53.860 us; speedup 1.0000x reference)
//
#include <hip/hip_runtime.h>

// DeepWalk hierarchical-softmax forward — round 4 (2nd resubmit; infra failures).
// Change vs R3: non-temporal (`nt`, no L2 allocation) loads for the
// ~zero-reuse traffic (deep tree levels shift 1..5, ~unique per element, and
// the center-embedding gather), while the high-reuse shallow levels
// (shift >= 6: only ~16 MB distinct serving 416 MB of logical reads) stay
// cacheable. This stops the streaming gathers from evicting the hot shallow
// rows out of the 4 MB per-XCD L2.

#define HS_NUM_NODES (1 << 19)
#define HS_LVLS 18          // levels i = 1 .. 18  (L = 19)
#define HS_DEEP  5          // shifts 1..5: treat as streaming (non-temporal)

typedef float v4f __attribute__((ext_vector_type(4)));

template <int N, int M>
__device__ inline void fold_step(float* w, int sub) {
    const bool hi = (sub & M) != 0;
    constexpr int NN = (N + 1) / 2;
#pragma unroll
    for (int k = 0; k < NN; ++k) {
        const float a = w[2 * k];
        const float b = (2 * k + 1 < N) ? w[2 * k + 1] : 0.f;
        const float keep = hi ? b : a;
        const float send = hi ? a : b;
        w[k] = keep + __shfl_xor(send, M, 64);   // M<=16: never crosses halves
    }
}

__global__ __launch_bounds__(256) void hs_fwd_kernel(
    const int* __restrict__ center,
    const int* __restrict__ context,
    const float* __restrict__ emb,
    const float* __restrict__ probs,
    float* __restrict__ out,
    int B)
{
    const int tid  = blockIdx.x * blockDim.x + threadIdx.x;
    const int elem = tid >> 5;                 // one element per 32-lane group
    if (elem >= B) return;
    const int sub = threadIdx.x & 31;

    const int c   = center[elem];
    const int ctx = context[elem] + HS_NUM_NODES;

    // center embedding: ~unique per element -> non-temporal
    const v4f ec = __builtin_nontemporal_load(
        reinterpret_cast<const v4f*>(emb + (size_t)c * 128 + sub * 4));

    // Issue all 18 gathers before any compute.
    // Deep levels (i < HS_DEEP, shift 1..5): ~no reuse -> nt (skip L2 alloc).
    // Shallow levels: ~26x reuse on a ~16 MB hot set -> cacheable.
    v4f p[HS_LVLS];
#pragma unroll
    for (int i = 0; i < HS_LVLS; ++i) {
        const int node = ctx >> (i + 1);
        const v4f* addr = reinterpret_cast<const v4f*>(
            probs + (size_t)node * 128 + sub * 4);
        if (i < HS_DEEP)
            p[i] = __builtin_nontemporal_load(addr);
        else
            p[i] = *addr;
    }

    // Per-lane partial dot for each level.
    float w[HS_LVLS];
#pragma unroll
    for (int i = 0; i < HS_LVLS; ++i)
        w[i] = p[i].x * ec.x + p[i].y * ec.y + p[i].z * ec.z + p[i].w * ec.w;

    // Multi-value butterfly: 18 -> 9 -> 5 -> 3 -> 2 -> 1 values per lane.
    // Lane l ends holding the full dot for level l (lanes 18..31 masked).
    fold_step<18, 1>(w, sub);
    fold_step<9,  2>(w, sub);
    fold_step<5,  4>(w, sub);
    fold_step<3,  8>(w, sub);
    fold_step<2, 16>(w, sub);

    const int sh   = (sub < HS_LVLS) ? (sub + 1) : 1;
    const int node = ctx >> sh;
    const float S  = w[0];
    const float x  = (node & 1) ? -S : S;
    float ls = fminf(x, 0.f) - __logf(1.f + __expf(-fabsf(x)));
    ls = (sub < HS_LVLS) ? ls : 0.f;

    float acc = ls;
#pragma unroll
    for (int m = 16; m; m >>= 1) acc += __shfl_xor(acc, m, 64);

    if (sub == 0) out[elem] = -acc;
}

extern "C" void kernel_launch(void* const* d_in, const int* in_sizes, int n_in,
                              void* d_out, int out_size, void* d_ws, size_t ws_size,
                              hipStream_t stream) {
    const int*   center  = (const int*)d_in[0];
    const int*   context = (const int*)d_in[1];
    const float* emb     = (const float*)d_in[2];
    const float* probs   = (const float*)d_in[3];
    float*       out     = (float*)d_out;

    const int B = in_sizes[0];                 // 65536
    const int threads = 256;                   // 8 elements / block
    const int blocks  = (B * 32 + threads - 1) / threads;
    hs_fwd_kernel<<<blocks, threads, 0, stream>>>(center, context, emb, probs,
                                                  out, B);
}

// Round 7
// 51.133 us; speedup vs baseline: 1.0533x; 1.0533x over previous
//
#include <hip/hip_runtime.h>

// DeepWalk hierarchical-softmax forward — round 5.
// Changes vs R4: (1) revert non-temporal loads (measured +12% regression —
// caches were doing useful work on the "streaming" levels too);
// (2) occupancy attack: 64 lanes per element with float2 (8B/lane) instead of
// 32 lanes with float4. Row coverage per load instr is still 512B (full
// cachelines), but the in-flight gather buffer halves to 38 VGPR; with
// __launch_bounds__(256,8) the kernel should fit <=64 VGPR -> 8 waves/SIMD
// (vs est. 2-4 before) -> 2-4x the in-flight gathers for latency hiding.

#define HS_NUM_NODES (1 << 19)
#define HS_LVLS 18          // levels i = 1 .. 18  (L = 19)

// Multi-value fold butterfly step: N values/lane -> ceil(N/2), folding the
// lowest surviving value-index bit into lane bit log2(M). After all steps,
// lane l holds the full cross-lane sum of value l.
template <int N, int M>
__device__ inline void fold_step(float* w, int lane) {
    const bool hi = (lane & M) != 0;
    constexpr int NN = (N + 1) / 2;
#pragma unroll
    for (int k = 0; k < NN; ++k) {
        const float a = w[2 * k];
        const float b = (2 * k + 1 < N) ? w[2 * k + 1] : 0.f;
        const float keep = hi ? b : a;
        const float send = hi ? a : b;
        w[k] = keep + __shfl_xor(send, M, 64);
    }
}

__global__ __launch_bounds__(256, 8) void hs_fwd_kernel(
    const int* __restrict__ center,
    const int* __restrict__ context,
    const float* __restrict__ emb,
    const float* __restrict__ probs,
    float* __restrict__ out,
    int B)
{
    const int elem = blockIdx.x * (blockDim.x >> 6) + (threadIdx.x >> 6);
    if (elem >= B) return;
    const int lane = threadIdx.x & 63;

    const int c   = center[elem];
    const int ctx = context[elem] + HS_NUM_NODES;

    // center embedding fragment: 2 floats per lane (64 lanes x 8B = 512B row)
    const float2 ec =
        *reinterpret_cast<const float2*>(emb + (size_t)c * 128 + lane * 2);

    // Issue all 18 level gathers before any compute (deep vmcnt pipeline,
    // only 38 VGPRs of buffer).
    float2 p[HS_LVLS];
#pragma unroll
    for (int i = 0; i < HS_LVLS; ++i) {
        const int node = ctx >> (i + 1);
        p[i] = *reinterpret_cast<const float2*>(
            probs + (size_t)node * 128 + lane * 2);
    }

    float w[HS_LVLS];
#pragma unroll
    for (int i = 0; i < HS_LVLS; ++i)
        w[i] = p[i].x * ec.x + p[i].y * ec.y;

    // 18 -> 9 -> 5 -> 3 -> 2 -> 1 values/lane across 64 lanes; lane l ends
    // holding the full dot product for level l (lanes 18..31 zero, 32..63 zero).
    fold_step<18, 1>(w, lane);
    fold_step<9,  2>(w, lane);
    fold_step<5,  4>(w, lane);
    fold_step<3,  8>(w, lane);
    fold_step<2, 16>(w, lane);
    fold_step<1, 32>(w, lane);

    // Lane l handles level l; log-sigmoid issued once for all 18 levels.
    const int sh   = (lane < HS_LVLS) ? (lane + 1) : 1;
    const int node = ctx >> sh;
    const float S  = w[0];
    const float x  = (node & 1) ? -S : S;
    float ls = fminf(x, 0.f) - __logf(1.f + __expf(-fabsf(x)));
    ls = (lane < HS_LVLS) ? ls : 0.f;

    // Sum the 18 per-level terms across the wave.
    float acc = ls;
#pragma unroll
    for (int m = 32; m; m >>= 1) acc += __shfl_xor(acc, m, 64);

    if (lane == 0) out[elem] = -acc;
}

extern "C" void kernel_launch(void* const* d_in, const int* in_sizes, int n_in,
                              void* d_out, int out_size, void* d_ws, size_t ws_size,
                              hipStream_t stream) {
    const int*   center  = (const int*)d_in[0];
    const int*   context = (const int*)d_in[1];
    const float* emb     = (const float*)d_in[2];
    const float* probs   = (const float*)d_in[3];
    float*       out     = (float*)d_out;

    const int B = in_sizes[0];                 // 65536
    const int threads = 256;                   // 4 elements / block (64 lanes each)
    const int blocks  = (B * 64 + threads - 1) / threads;
    hs_fwd_kernel<<<blocks, threads, 0, stream>>>(center, context, emb, probs,
                                                  out, B);
}